// Round 19
// baseline (48.877 us; speedup 1.0000x reference)
//
#include <hip/hip_runtime.h>
#include <hip/hip_bf16.h>
#include <cstdint>
#include <cstddef>

// Spatiotemporal dual-softmax attention, MI355X (gfx950).
// B=4, C=64, CI=32, N=H*W=4096. Flash-style, never materializes the 4096^2
// energy matrix. Round-19 = round-18 (47.7 us) with ONE change: the B panel
// (th/ph) is staged via global_load_lds DMA. th/ph are stored PRE-PADDED
// [N][40] bf16 in global, so each 256-row window is one contiguous 20480-B
// span; linear wave-uniform DMA into the padded [256][40] LDS buffer
// reproduces the layout exactly (pad copied, never read; fragment reads
// keep the proven stride-40 addressing). Per window this replaces 1024
// reg-loads + 1024 ds_writes block-wide with 20 DMA issues. V stays
// reg-staged (row-strided global layout is DMA-incompatible).
//   proj  (512 blk x 512): MFMA projections (r18-proven), th/ph stride 40.
//   apply (512 blk x 512): 8 waves = 2 rg x 4 cg, 256-col windows x 16,
//         2-chunk inner loop, double-buffered LDS, one barrier per window.
//         Energy MFMA (swapped operands) -> exp2 (theta pre-scaled by log2e;
//         energies provably << 80, no max subtraction) -> bf16 pack -> K=16
//         PV MFMA. Row-sums via ones-MFMA; s_setprio(1) around compute.
//         Epilogue: 4-way cg combine, normalize, output conv+BN+residual.

#define B_  4
#define C_  64
#define CI_ 32
#define N_  4096
#define APITCH_ 40                      // padded row pitch (shorts) for th/ph
static constexpr float EPS_   = 1e-5f;
static constexpr float LOG2E_ = 1.4426950408889634f;

typedef __attribute__((ext_vector_type(8))) short  short8;
typedef __attribute__((ext_vector_type(4))) short  short4v;
typedef __attribute__((ext_vector_type(4))) float  float4v;
typedef __attribute__((ext_vector_type(4))) __bf16 bf16x4;

__device__ __forceinline__ short f2bf(float f) {
    unsigned u = __float_as_uint(f);
    unsigned r = (u + 0x7fffu + ((u >> 16) & 1u)) >> 16;   // RNE
    return (short)r;
}

__device__ __forceinline__ float4v mfma16(short4v a, short4v b, float4v c) {
#if __has_builtin(__builtin_amdgcn_mfma_f32_16x16x16bf16_1k)
    return __builtin_amdgcn_mfma_f32_16x16x16bf16_1k(a, b, c, 0, 0, 0);
#else
    float4v d;
    asm("v_mfma_f32_16x16x16_bf16 %0, %1, %2, %3" : "=v"(d) : "v"(a), "v"(b), "v"(c));
    return d;
#endif
}

__device__ __forceinline__ void gload_lds16(const short* g, char* l) {
    __builtin_amdgcn_global_load_lds(
        (const __attribute__((address_space(1))) void*)g,
        (__attribute__((address_space(3))) void*)l, 16, 0, 0);
}

// ---------------------------------------------------------------------------
// MFMA projections (r18-proven). side = blk>>8: 0: x1 -> {theta*log2e, g1};
// 1: x2 -> {phi, g2}. theta/phi: [b][n][APITCH] padded frag layout; g:
// [b][32][n] row-major (V layout). 64 n-cols per block.
// 8 waves = set(2) x oTile(2) x nPair(2); each wave: 2 nTiles x 2 K-MFMAs.
// ---------------------------------------------------------------------------
__global__ __launch_bounds__(512) void proj_kernel(
    const float* __restrict__ x1, const float* __restrict__ x2,
    const float* __restrict__ g_w, const float* __restrict__ g_b, const float* __restrict__ g_bn,
    const float* __restrict__ t_w, const float* __restrict__ t_b, const float* __restrict__ t_bn,
    const float* __restrict__ p_w, const float* __restrict__ p_b, const float* __restrict__ p_bn,
    short* __restrict__ th_t, short* __restrict__ ph_t,
    short* __restrict__ g1l, short* __restrict__ g2l)
{
    const int side = blockIdx.x >> 8;
    const int rb   = blockIdx.x & 255;
    const int b    = rb >> 6;
    const int n0   = (rb & 63) * 64;
    const int tid  = threadIdx.x;
    const int wv   = tid >> 6, lane = tid & 63;
    const int lg   = lane >> 4, lr = lane & 15;

    const float* x   = side ? x2   : x1;
    const float* wA  = side ? p_w  : t_w;
    const float* bA  = side ? p_b  : t_b;
    const float* bnA = side ? p_bn : t_bn;
    short* outA      = side ? ph_t : th_t;
    short* outG      = side ? g2l  : g1l;
    const float scaleA = side ? 1.0f : LOG2E_;   // theta carries log2e

    __shared__ short xs_t[64][72];      // 9216 B  X^T: [n][c] bf16 (pad 72)
    __shared__ short wfb[2][32][72];    // 9216 B  [set][o][c] bf16 (pad 72)
    __shared__ float bfold[2][CI_];

    for (int it = 0; it < 4; it++) {                 // fold both weight sets
        int idx = it * 512 + tid;                    // [o][c] flat, 2048
        int o = idx >> 6, c = idx & 63;
        float invA = bnA[c]  * rsqrtf(bnA[192 + c]  + EPS_);
        float invG = g_bn[c] * rsqrtf(g_bn[192 + c] + EPS_);
        wfb[0][o][c] = f2bf(wA[idx]  * invA * scaleA);
        wfb[1][o][c] = f2bf(g_w[idx] * invG);
    }
    if (tid < 2 * CI_) {
        int set = tid >> 5, o = tid & 31;
        const float* bn = set ? g_bn : bnA;
        const float* w  = set ? g_w  : wA;
        const float* bs = set ? g_b  : bA;
        float s = bs[o];
        for (int c = 0; c < C_; c++) {
            float inv = bn[c] * rsqrtf(bn[192 + c] + EPS_);
            s += w[o * C_ + c] * (bn[64 + c] - bn[128 + c] * inv);
        }
        bfold[set][o] = set ? s : s * scaleA;
    }
    const float* xb = x + (size_t)b * C_ * N_ + n0;
    for (int it = 0; it < 2; it++) {                 // stage X^T as bf16
        int idx = it * 512 + tid;                    // 1024 float4 pieces
        int c = idx >> 4, nq = idx & 15;
        float4 xv = *(const float4*)(xb + (size_t)c * N_ + nq * 4);
        xs_t[nq * 4 + 0][c] = f2bf(xv.x);
        xs_t[nq * 4 + 1][c] = f2bf(xv.y);
        xs_t[nq * 4 + 2][c] = f2bf(xv.z);
        xs_t[nq * 4 + 3][c] = f2bf(xv.w);
    }
    __syncthreads();

    const int set = wv & 1;              // 0 = theta/phi, 1 = g
    const int oT  = (wv >> 1) & 1;       // o tile: o = oT*16 + lg*4 + i
    const int nP  = wv >> 2;             // n pair: nTiles {2nP, 2nP+1}

    const float4v zero4 = {0.f, 0.f, 0.f, 0.f};
    // W A-frags (lane: A[row = oT*16+lr][k = c0 + lg*8 + j])
    short8 wf0 = *(const short8*)&wfb[set][oT * 16 + lr][lg * 8];
    short8 wf1 = *(const short8*)&wfb[set][oT * 16 + lr][32 + lg * 8];
    float4v cinit = zero4;
#pragma unroll
    for (int i = 0; i < 4; ++i) cinit[i] = bfold[set][oT * 16 + lg * 4 + i];

#pragma unroll
    for (int t = 0; t < 2; ++t) {
        const int nT = nP * 2 + t;
        // X B-frags (lane: B[k = c0 + lg*8 + j][col = nT*16 + lr])
        short8 xf0 = *(const short8*)&xs_t[nT * 16 + lr][lg * 8];
        short8 xf1 = *(const short8*)&xs_t[nT * 16 + lr][32 + lg * 8];
        float4v d = __builtin_amdgcn_mfma_f32_16x16x32_bf16(wf0, xf0, cinit, 0, 0, 0);
        d = __builtin_amdgcn_mfma_f32_16x16x32_bf16(wf1, xf1, d, 0, 0, 0);
        // d[i] = out[o = oT*16 + lg*4 + i][n = n0 + nT*16 + lr]
        const int n = n0 + nT * 16 + lr;
        if (set == 0) {
            short4v v;
#pragma unroll
            for (int i = 0; i < 4; ++i) v[i] = f2bf(d[i]);
            *(short4v*)(outA + ((size_t)b * N_ + n) * APITCH_ + oT * 16 + lg * 4) = v;
        } else {
#pragma unroll
            for (int i = 0; i < 4; ++i)
                outG[((size_t)b * CI_ + oT * 16 + lg * 4 + i) * N_ + n] = f2bf(d[i]);
        }
    }
}

// ---------------------------------------------------------------------------
// Apply (fused softmax-sum + PV + output conv + residual).
// 8 waves = 2 rg x 4 cg. Per 256-col window, wave (rg,cg) computes its 32
// m-rows against chunks ch2*128 + cg*32 for ch2 = 0,1. B panel DMA'd via
// global_load_lds (contiguous padded span); V reg-staged issue-early /
// write-late; ONE barrier per window. Sums via ones-MFMA; setprio(1).
// ---------------------------------------------------------------------------
__global__ __launch_bounds__(512, 6) void apply_kernel(
    const short* __restrict__ th, const short* __restrict__ ph,
    const short* __restrict__ g1l, const short* __restrict__ g2l,
    const float* __restrict__ x1, const float* __restrict__ x2,
    const float* __restrict__ Ww, const float* __restrict__ Wb,
    const float* __restrict__ w_bn,
    float* __restrict__ out)
{
    const int side = blockIdx.x >> 8;
    const int rb   = blockIdx.x & 255;
    const short* A  = side ? th : ph;       // rows = softmax/output dim (m)
    const short* Bm = side ? ph : th;       // cols = reduction dim (n)
    const short* V  = side ? g2l : g1l;
    const int b  = rb >> 6;
    const int r0 = (rb & 63) * 64;
    const int tid = threadIdx.x;
    const int wv = tid >> 6, lane = tid & 63;
    const int cg = wv & 3, rg = wv >> 2;
    const int lg = lane >> 4, lr = lane & 15;

    // main loop: lb [2][256][40]s = 40960 | lv [2][32][264]s = 33792 -> 74752
    __shared__ __align__(16) char smem[74752];
    short (*lb)[256][40] = (short(*)[256][40])smem;
    short (*lv)[32][264] = (short(*)[32][264])(smem + 40960);
    // epilogue overlays (dead vs main loop across barriers)
    float (*buf2)[64][33] = (float(*)[64][33])smem;            // 16896
    float (*sums)[64]     = (float(*)[64])(smem + 16896);      //  1024
    float (*ybuf)[36]     = (float(*)[36])(smem + 17920);      //  9216
    float (*wf2)[CI_]     = (float(*)[CI_])(smem + 27136);     //  8192
    float *bf2v           = (float*)(smem + 35328);            //   256

    const short* Ab = A  + (size_t)b * N_ * APITCH_;
    const short* Bb = Bm + (size_t)b * N_ * APITCH_;
    const short* Vb = V  + (size_t)b * CI_ * N_;

    short8 afrag0 = *(const short8*)(Ab + (size_t)(r0 + rg * 32 + lr) * APITCH_ + lg * 8);
    short8 afrag1 = *(const short8*)(Ab + (size_t)(r0 + rg * 32 + 16 + lr) * APITCH_ + lg * 8);

    short4v ones;
    ones[0] = ones[1] = ones[2] = ones[3] = (short)0x3F80;   // bf16 1.0

    const float4v zero4 = {0.f, 0.f, 0.f, 0.f};
    float4v a00 = zero4, a01 = zero4;   // t=0: y[ci=4lg+i][m], y[16+4lg+i][m]
    float4v a10 = zero4, a11 = zero4;   // t=1 (m + 16)
    float4v sum0 = zero4, sum1 = zero4; // ones-MFMA sum accumulators

    // B DMA: one window = 256 rows x 80 B = 20480 B, contiguous in global
    // (padded [N][40]). 20 wave-loads of 1024 B; wave wv does {wv, wv+8, wv+16}.
    const short* BwinBase = Bb;                      // + win*256*APITCH_
    // V staging (reg): 32 rows x 256 bf16 = 1024 pieces, 2 per thread
    const int vrow0 = tid >> 5,          vpart0 = tid & 31;
    const int vrow1 = (512 + tid) >> 5,  vpart1 = (512 + tid) & 31;
    const short* gV0 = Vb + (size_t)vrow0 * N_ + vpart0 * 8;
    const short* gV1 = Vb + (size_t)vrow1 * N_ + vpart1 * 8;

    {   // prologue: stage window 0 into buffer 0
        for (int j = wv; j < 20; j += 8)
            gload_lds16(BwinBase + (size_t)j * 512 + lane * 8,
                        (char*)&lb[0][0][0] + j * 1024);
        short8 v0s = *(const short8*)gV0;
        short8 v1s = *(const short8*)gV1;
        *(short8*)&lv[0][vrow0][vpart0 * 8] = v0s;
        *(short8*)&lv[0][vrow1][vpart1 * 8] = v1s;
    }
    __syncthreads();

    int cur = 0;
    for (int win = 0; win < 16; ++win) {
        short8 vst0, vst1;
        if (win < 15) {                              // issue next window early
            const int s0n = (win + 1) * 256;
            // B: DMA directly into the other buffer (region not in use)
            const short* Bw = BwinBase + (size_t)s0n * APITCH_;
            char* ldst = (char*)&lb[cur ^ 1][0][0];
            for (int j = wv; j < 20; j += 8)
                gload_lds16(Bw + (size_t)j * 512 + lane * 8, ldst + j * 1024);
            vst0 = *(const short8*)(gV0 + s0n);
            vst1 = *(const short8*)(gV1 + s0n);
        }
        // ---- compute window `win` from buffer `cur` ----
        __builtin_amdgcn_s_setprio(1);
#pragma unroll
        for (int ch2 = 0; ch2 < 2; ++ch2) {
            const int c0 = ch2 * 128 + cg * 32;      // window-local col base
            short8 b0 = *(const short8*)&lb[cur][c0 + lr][lg * 8];
            short8 b1 = *(const short8*)&lb[cur][c0 + 16 + lr][lg * 8];
            short4v v00 = *(const short4v*)&lv[cur][lr][c0 + lg * 4];
            short4v v01 = *(const short4v*)&lv[cur][lr][c0 + 16 + lg * 4];
            short4v v10 = *(const short4v*)&lv[cur][16 + lr][c0 + lg * 4];
            short4v v11 = *(const short4v*)&lv[cur][16 + lr][c0 + 16 + lg * 4];
            {   // t = 0 (m rows r0 + rg*32 + lr)
                float4v e0 = __builtin_amdgcn_mfma_f32_16x16x32_bf16(b0, afrag0, zero4, 0, 0, 0);
                float4v e1 = __builtin_amdgcn_mfma_f32_16x16x32_bf16(b1, afrag0, zero4, 0, 0, 0);
                float p0 = __builtin_amdgcn_exp2f(e0[0]), p1 = __builtin_amdgcn_exp2f(e0[1]);
                float p2 = __builtin_amdgcn_exp2f(e0[2]), p3 = __builtin_amdgcn_exp2f(e0[3]);
                float p4 = __builtin_amdgcn_exp2f(e1[0]), p5 = __builtin_amdgcn_exp2f(e1[1]);
                float p6 = __builtin_amdgcn_exp2f(e1[2]), p7 = __builtin_amdgcn_exp2f(e1[3]);
                bf16x4 q0, q1;
                q0[0] = (__bf16)p0; q0[1] = (__bf16)p1; q0[2] = (__bf16)p2; q0[3] = (__bf16)p3;
                q1[0] = (__bf16)p4; q1[1] = (__bf16)p5; q1[2] = (__bf16)p6; q1[3] = (__bf16)p7;
                short4v pk0 = __builtin_bit_cast(short4v, q0);
                short4v pk1 = __builtin_bit_cast(short4v, q1);
                a00  = mfma16(v00, pk0, a00);
                a00  = mfma16(v01, pk1, a00);
                a01  = mfma16(v10, pk0, a01);
                a01  = mfma16(v11, pk1, a01);
                sum0 = mfma16(ones, pk0, sum0);      // row r of D = colsum(P)
                sum0 = mfma16(ones, pk1, sum0);
            }
            {   // t = 1 (m rows r0 + rg*32 + 16 + lr)
                float4v e0 = __builtin_amdgcn_mfma_f32_16x16x32_bf16(b0, afrag1, zero4, 0, 0, 0);
                float4v e1 = __builtin_amdgcn_mfma_f32_16x16x32_bf16(b1, afrag1, zero4, 0, 0, 0);
                float p0 = __builtin_amdgcn_exp2f(e0[0]), p1 = __builtin_amdgcn_exp2f(e0[1]);
                float p2 = __builtin_amdgcn_exp2f(e0[2]), p3 = __builtin_amdgcn_exp2f(e0[3]);
                float p4 = __builtin_amdgcn_exp2f(e1[0]), p5 = __builtin_amdgcn_exp2f(e1[1]);
                float p6 = __builtin_amdgcn_exp2f(e1[2]), p7 = __builtin_amdgcn_exp2f(e1[3]);
                bf16x4 q0, q1;
                q0[0] = (__bf16)p0; q0[1] = (__bf16)p1; q0[2] = (__bf16)p2; q0[3] = (__bf16)p3;
                q1[0] = (__bf16)p4; q1[1] = (__bf16)p5; q1[2] = (__bf16)p6; q1[3] = (__bf16)p7;
                short4v pk0 = __builtin_bit_cast(short4v, q0);
                short4v pk1 = __builtin_bit_cast(short4v, q1);
                a10  = mfma16(v00, pk0, a10);
                a10  = mfma16(v01, pk1, a10);
                a11  = mfma16(v10, pk0, a11);
                a11  = mfma16(v11, pk1, a11);
                sum1 = mfma16(ones, pk0, sum1);
                sum1 = mfma16(ones, pk1, sum1);
            }
        }
        __builtin_amdgcn_s_setprio(0);
        if (win < 15) {                              // V write-late, other buf
            *(short8*)&lv[cur ^ 1][vrow0][vpart0 * 8] = vst0;
            *(short8*)&lv[cur ^ 1][vrow1][vpart1 * 8] = vst1;
        }
        __syncthreads();                             // one barrier per window
        cur ^= 1;                                    // (drains DMA vmcnt too)
    }

    // every lane's sum*[0] = exp-sum partial for its m-row (all rows of the
    // ones-MFMA D are identical); no cross-lane reduce needed.
    const float s0r = sum0[0];
    const float s1r = sum1[0];

    // (last barrier of the loop separates main-loop LDS use from overlays)
    if (cg >= 2) {                                   // seed buf2[cg-2]
        float* r0p = buf2[cg - 2][rg * 32 + lr];
        float* r1p = buf2[cg - 2][rg * 32 + 16 + lr];
#pragma unroll
        for (int i = 0; i < 4; ++i) {
            r0p[4 * lg + i]      = a00[i];
            r0p[16 + 4 * lg + i] = a01[i];
            r1p[4 * lg + i]      = a10[i];
            r1p[16 + 4 * lg + i] = a11[i];
        }
    }
    if (lane < 16) {
        sums[cg][rg * 32 + lane]      = s0r;
        sums[cg][rg * 32 + 16 + lane] = s1r;
    }
    for (int i = tid; i < C_ * CI_; i += 512) {      // fold output weights
        int co = i >> 5;
        float inv = w_bn[co] * rsqrtf(w_bn[192 + co] + EPS_);
        (&wf2[0][0])[i] = inv * Ww[i];               // flat [co][ci]
    }
    if (tid < C_) {
        float inv = w_bn[tid] * rsqrtf(w_bn[192 + tid] + EPS_);
        bf2v[tid] = inv * Wb[tid] + (w_bn[64 + tid] - w_bn[128 + tid] * inv);
    }
    __syncthreads();                                 // E1
    if (cg < 2) {                                    // add into buf2[cg]
        float* r0p = buf2[cg][rg * 32 + lr];
        float* r1p = buf2[cg][rg * 32 + 16 + lr];
#pragma unroll
        for (int i = 0; i < 4; ++i) {
            r0p[4 * lg + i]      += a00[i];
            r0p[16 + 4 * lg + i] += a01[i];
            r1p[4 * lg + i]      += a10[i];
            r1p[16 + 4 * lg + i] += a11[i];
        }
    }
    __syncthreads();                                 // E2
    {   // combine 2 buffers + 4 sums, normalize -> ybuf (512 thr: 4 elems)
        int m = tid >> 3;
        int ci0 = (tid & 7) * 4;
        float s = (sums[0][m] + sums[1][m]) + (sums[2][m] + sums[3][m]);
        float inv = 1.0f / s;
#pragma unroll
        for (int q = 0; q < 4; ++q) {
            ybuf[m][ci0 + q] = (buf2[0][m][ci0 + q] + buf2[1][m][ci0 + q]) * inv;
        }
    }
    __syncthreads();                                 // E3

    // fused output conv + BN + residual: out[co][m] = x[co][m] + sum_ci wf2*y
    const int m   = tid & 63;
    const int cog = tid >> 6;                        // wave handles co = 8*cog..+7
    float4v yq[8];
#pragma unroll
    for (int q = 0; q < 8; ++q) yq[q] = *(const float4v*)&ybuf[m][q * 4];
    const float* xb2 = (side ? x2 : x1) + (size_t)b * C_ * N_;
    float* ob = out + (size_t)side * (B_ * C_ * N_) + (size_t)b * C_ * N_;
#pragma unroll
    for (int k = 0; k < 8; ++k) {
        const int co = cog * 8 + k;
        float a2 = bf2v[co];
#pragma unroll
        for (int ci = 0; ci < CI_; ++ci) a2 += wf2[co][ci] * yq[ci >> 2][ci & 3];
        ob[(size_t)co * N_ + r0 + m] = xb2[(size_t)co * N_ + r0 + m] + a2;
    }
}

// ---------------------------------------------------------------------------
extern "C" void kernel_launch(void* const* d_in, const int* in_sizes, int n_in,
                              void* d_out, int out_size, void* d_ws, size_t ws_size,
                              hipStream_t stream)
{
    (void)in_sizes; (void)n_in; (void)out_size; (void)ws_size;
    const float* x1   = (const float*)d_in[0];
    const float* x2   = (const float*)d_in[1];
    const float* g_bn = (const float*)d_in[2];
    const float* g_w  = (const float*)d_in[3];
    const float* g_b  = (const float*)d_in[4];
    const float* t_bn = (const float*)d_in[5];
    const float* t_w  = (const float*)d_in[6];
    const float* t_b  = (const float*)d_in[7];
    const float* p_bn = (const float*)d_in[8];
    const float* p_w  = (const float*)d_in[9];
    const float* p_b  = (const float*)d_in[10];
    const float* w_bn = (const float*)d_in[11];
    const float* W_w  = (const float*)d_in[12];
    const float* W_b  = (const float*)d_in[13];
    float* out = (float*)d_out;

    char* ws = (char*)d_ws;
    const size_t MB = 1u << 20;
    // th/ph: [B][N][40] bf16 padded = 1.31 MB each (theta pre-scaled log2e)
    short* th_t = (short*)(ws + 0);
    short* ph_t = (short*)(ws + 2 * MB);
    short* g1l  = (short*)(ws + 4 * MB);             // [B][32][N] bf16
    short* g2l  = (short*)(ws + 5 * MB);             // [B][32][N] bf16

    proj_kernel<<<dim3(512), dim3(512), 0, stream>>>(
        x1, x2, g_w, g_b, g_bn, t_w, t_b, t_bn, p_w, p_b, p_bn,
        th_t, ph_t, g1l, g2l);

    apply_kernel<<<dim3(512), dim3(512), 0, stream>>>(
        th_t, ph_t, g1l, g2l, x1, x2, W_w, W_b, w_bn, out);
}

// Round 20
// 46.259 us; speedup vs baseline: 1.0566x; 1.0566x over previous
//
#include <hip/hip_runtime.h>
#include <hip/hip_bf16.h>
#include <cstdint>
#include <cstddef>

// Spatiotemporal dual-softmax attention, MI355X (gfx950).
// B=4, C=64, CI=32, N=H*W=4096. Flash-style, never materializes the 4096^2
// energy matrix. Round-20 = round-18 (best, 47.7 us; r19's DMA B-staging was
// neutral-negative and is reverted) + ONE change: XCD-aware block remap in
// apply (T1). Grid 512 = 8 (side,b) groups x 64 r0-blocks; default dispatch
// round-robins consecutive blocks over 8 XCDs, so every XCD caches every
// 1 MB panel (64 MB demand vs 32 MB aggregate L2 -> FETCH ~2.5x ideal).
// Remap g = bid&7 (-> XCD), j = bid>>3: each XCD serves exactly one panel
// from its private L2. Bijective; proj untouched.
//   proj  (512 blk x 512): MFMA projections (r18-proven).
//   apply (512 blk x 512): 8 waves = 2 rg x 4 cg, 256-col windows x 16,
//         2-chunk inner loop, double-buffered LDS, reg-staged issue-early /
//         write-late (T14), one barrier per window. Energy MFMA (swapped
//         operands) -> exp2 (theta pre-scaled by log2e; energies provably
//         << 80, no max subtraction) -> bf16 pack -> K=16 PV MFMA.
//         Row-sums via ones-MFMA; s_setprio(1) around compute.
//         Epilogue: 4-way cg combine, normalize, output conv+BN+residual.

#define B_  4
#define C_  64
#define CI_ 32
#define N_  4096
static constexpr float EPS_   = 1e-5f;
static constexpr float LOG2E_ = 1.4426950408889634f;

typedef __attribute__((ext_vector_type(8))) short  short8;
typedef __attribute__((ext_vector_type(4))) short  short4v;
typedef __attribute__((ext_vector_type(4))) float  float4v;
typedef __attribute__((ext_vector_type(4))) __bf16 bf16x4;

__device__ __forceinline__ short f2bf(float f) {
    unsigned u = __float_as_uint(f);
    unsigned r = (u + 0x7fffu + ((u >> 16) & 1u)) >> 16;   // RNE
    return (short)r;
}

__device__ __forceinline__ float4v mfma16(short4v a, short4v b, float4v c) {
#if __has_builtin(__builtin_amdgcn_mfma_f32_16x16x16bf16_1k)
    return __builtin_amdgcn_mfma_f32_16x16x16bf16_1k(a, b, c, 0, 0, 0);
#else
    float4v d;
    asm("v_mfma_f32_16x16x16_bf16 %0, %1, %2, %3" : "=v"(d) : "v"(a), "v"(b), "v"(c));
    return d;
#endif
}

// ---------------------------------------------------------------------------
// MFMA projections (r18-proven). side = blk>>8: 0: x1 -> {theta*log2e, g1};
// 1: x2 -> {phi, g2}. theta/phi: [b][n][32] frag layout (scale folded into
// weights+bias); g: [b][32][n] row-major (V layout). 64 n-cols per block.
// 8 waves = set(2) x oTile(2) x nPair(2); each wave: 2 nTiles x 2 K-MFMAs.
// ---------------------------------------------------------------------------
__global__ __launch_bounds__(512) void proj_kernel(
    const float* __restrict__ x1, const float* __restrict__ x2,
    const float* __restrict__ g_w, const float* __restrict__ g_b, const float* __restrict__ g_bn,
    const float* __restrict__ t_w, const float* __restrict__ t_b, const float* __restrict__ t_bn,
    const float* __restrict__ p_w, const float* __restrict__ p_b, const float* __restrict__ p_bn,
    short* __restrict__ th_t, short* __restrict__ ph_t,
    short* __restrict__ g1l, short* __restrict__ g2l)
{
    const int side = blockIdx.x >> 8;
    const int rb   = blockIdx.x & 255;
    const int b    = rb >> 6;
    const int n0   = (rb & 63) * 64;
    const int tid  = threadIdx.x;
    const int wv   = tid >> 6, lane = tid & 63;
    const int lg   = lane >> 4, lr = lane & 15;

    const float* x   = side ? x2   : x1;
    const float* wA  = side ? p_w  : t_w;
    const float* bA  = side ? p_b  : t_b;
    const float* bnA = side ? p_bn : t_bn;
    short* outA      = side ? ph_t : th_t;
    short* outG      = side ? g2l  : g1l;
    const float scaleA = side ? 1.0f : LOG2E_;   // theta carries log2e

    __shared__ short xs_t[64][72];      // 9216 B  X^T: [n][c] bf16 (pad 72)
    __shared__ short wfb[2][32][72];    // 9216 B  [set][o][c] bf16 (pad 72)
    __shared__ float bfold[2][CI_];

    for (int it = 0; it < 4; it++) {                 // fold both weight sets
        int idx = it * 512 + tid;                    // [o][c] flat, 2048
        int o = idx >> 6, c = idx & 63;
        float invA = bnA[c]  * rsqrtf(bnA[192 + c]  + EPS_);
        float invG = g_bn[c] * rsqrtf(g_bn[192 + c] + EPS_);
        wfb[0][o][c] = f2bf(wA[idx]  * invA * scaleA);
        wfb[1][o][c] = f2bf(g_w[idx] * invG);
    }
    if (tid < 2 * CI_) {
        int set = tid >> 5, o = tid & 31;
        const float* bn = set ? g_bn : bnA;
        const float* w  = set ? g_w  : wA;
        const float* bs = set ? g_b  : bA;
        float s = bs[o];
        for (int c = 0; c < C_; c++) {
            float inv = bn[c] * rsqrtf(bn[192 + c] + EPS_);
            s += w[o * C_ + c] * (bn[64 + c] - bn[128 + c] * inv);
        }
        bfold[set][o] = set ? s : s * scaleA;
    }
    const float* xb = x + (size_t)b * C_ * N_ + n0;
    for (int it = 0; it < 2; it++) {                 // stage X^T as bf16
        int idx = it * 512 + tid;                    // 1024 float4 pieces
        int c = idx >> 4, nq = idx & 15;
        float4 xv = *(const float4*)(xb + (size_t)c * N_ + nq * 4);
        xs_t[nq * 4 + 0][c] = f2bf(xv.x);
        xs_t[nq * 4 + 1][c] = f2bf(xv.y);
        xs_t[nq * 4 + 2][c] = f2bf(xv.z);
        xs_t[nq * 4 + 3][c] = f2bf(xv.w);
    }
    __syncthreads();

    const int set = wv & 1;              // 0 = theta/phi, 1 = g
    const int oT  = (wv >> 1) & 1;       // o tile: o = oT*16 + lg*4 + i
    const int nP  = wv >> 2;             // n pair: nTiles {2nP, 2nP+1}

    const float4v zero4 = {0.f, 0.f, 0.f, 0.f};
    // W A-frags (lane: A[row = oT*16+lr][k = c0 + lg*8 + j])
    short8 wf0 = *(const short8*)&wfb[set][oT * 16 + lr][lg * 8];
    short8 wf1 = *(const short8*)&wfb[set][oT * 16 + lr][32 + lg * 8];
    float4v cinit = zero4;
#pragma unroll
    for (int i = 0; i < 4; ++i) cinit[i] = bfold[set][oT * 16 + lg * 4 + i];

#pragma unroll
    for (int t = 0; t < 2; ++t) {
        const int nT = nP * 2 + t;
        // X B-frags (lane: B[k = c0 + lg*8 + j][col = nT*16 + lr])
        short8 xf0 = *(const short8*)&xs_t[nT * 16 + lr][lg * 8];
        short8 xf1 = *(const short8*)&xs_t[nT * 16 + lr][32 + lg * 8];
        float4v d = __builtin_amdgcn_mfma_f32_16x16x32_bf16(wf0, xf0, cinit, 0, 0, 0);
        d = __builtin_amdgcn_mfma_f32_16x16x32_bf16(wf1, xf1, d, 0, 0, 0);
        // d[i] = out[o = oT*16 + lg*4 + i][n = n0 + nT*16 + lr]
        const int n = n0 + nT * 16 + lr;
        if (set == 0) {
            short4v v;
#pragma unroll
            for (int i = 0; i < 4; ++i) v[i] = f2bf(d[i]);
            *(short4v*)(outA + ((size_t)b * N_ + n) * CI_ + oT * 16 + lg * 4) = v;
        } else {
#pragma unroll
            for (int i = 0; i < 4; ++i)
                outG[((size_t)b * CI_ + oT * 16 + lg * 4 + i) * N_ + n] = f2bf(d[i]);
        }
    }
}

// ---------------------------------------------------------------------------
// Apply (fused softmax-sum + PV + output conv + residual).
// XCD-aware decode: g = bid&7 -> (side,b) group pinned to one XCD's L2;
// j = bid>>3 -> r0-block. 8 waves = 2 rg x 4 cg. Per 256-col window, wave
// (rg,cg) computes its 32 m-rows against chunks ch2*128 + cg*32, ch2 = 0,1.
// Double-buffered LDS; reg-staged issue-early / write-late; ONE barrier per
// window. Sums via ones-MFMA; setprio(1) around the compute region.
// ---------------------------------------------------------------------------
__global__ __launch_bounds__(512, 6) void apply_kernel(
    const short* __restrict__ th, const short* __restrict__ ph,
    const short* __restrict__ g1l, const short* __restrict__ g2l,
    const float* __restrict__ x1, const float* __restrict__ x2,
    const float* __restrict__ Ww, const float* __restrict__ Wb,
    const float* __restrict__ w_bn,
    float* __restrict__ out)
{
    const int bid  = blockIdx.x;
    const int grp  = bid & 7;               // (side,b) group -> XCD affinity
    const int side = grp >> 2;
    const int b    = grp & 3;
    const int r0   = (bid >> 3) * 64;
    const short* A  = side ? th : ph;       // rows = softmax/output dim (m)
    const short* Bm = side ? ph : th;       // cols = reduction dim (n)
    const short* V  = side ? g2l : g1l;
    const int tid = threadIdx.x;
    const int wv = tid >> 6, lane = tid & 63;
    const int cg = wv & 3, rg = wv >> 2;
    const int lg = lane >> 4, lr = lane & 15;

    // main loop: lb [2][256][40]s = 40960 | lv [2][32][264]s = 33792 -> 74752
    __shared__ __align__(16) char smem[74752];
    short (*lb)[256][40] = (short(*)[256][40])smem;
    short (*lv)[32][264] = (short(*)[32][264])(smem + 40960);
    // epilogue overlays (dead vs main loop across barriers)
    float (*buf2)[64][33] = (float(*)[64][33])smem;            // 16896
    float (*sums)[64]     = (float(*)[64])(smem + 16896);      //  1024
    float (*ybuf)[36]     = (float(*)[36])(smem + 17920);      //  9216
    float (*wf2)[CI_]     = (float(*)[CI_])(smem + 27136);     //  8192
    float *bf2v           = (float*)(smem + 35328);            //   256

    const short* Ab = A  + (size_t)b * N_ * CI_;
    const short* Bb = Bm + (size_t)b * N_ * CI_;
    const short* Vb = V  + (size_t)b * CI_ * N_;

    short8 afrag0 = *(const short8*)(Ab + (size_t)(r0 + rg * 32 + lr) * CI_ + lg * 8);
    short8 afrag1 = *(const short8*)(Ab + (size_t)(r0 + rg * 32 + 16 + lr) * CI_ + lg * 8);

    short4v ones;
    ones[0] = ones[1] = ones[2] = ones[3] = (short)0x3F80;   // bf16 1.0

    const float4v zero4 = {0.f, 0.f, 0.f, 0.f};
    float4v a00 = zero4, a01 = zero4;   // t=0: y[ci=4lg+i][m], y[16+4lg+i][m]
    float4v a10 = zero4, a11 = zero4;   // t=1 (m + 16)
    float4v sum0 = zero4, sum1 = zero4; // ones-MFMA sum accumulators

    // staging: 256x32 B (1024 pieces) + 32x256 V (1024 pieces), 2 each/thread
    const int brow0 = tid >> 2,          bpart0 = tid & 3;          // it=0
    const int brow1 = (512 + tid) >> 2,  bpart1 = (512 + tid) & 3;  // it=1
    const int vrow0 = tid >> 5,          vpart0 = tid & 31;
    const int vrow1 = (512 + tid) >> 5,  vpart1 = (512 + tid) & 31;
    const short* gB0 = Bb + (size_t)brow0 * CI_ + bpart0 * 8;
    const short* gB1 = Bb + (size_t)brow1 * CI_ + bpart1 * 8;
    const short* gV0 = Vb + (size_t)vrow0 * N_ + vpart0 * 8;
    const short* gV1 = Vb + (size_t)vrow1 * N_ + vpart1 * 8;

    {   // prologue: stage window 0 into buffer 0
        short8 b0s = *(const short8*)gB0;
        short8 b1s = *(const short8*)gB1;
        short8 v0s = *(const short8*)gV0;
        short8 v1s = *(const short8*)gV1;
        *(short8*)&lb[0][brow0][bpart0 * 8] = b0s;
        *(short8*)&lb[0][brow1][bpart1 * 8] = b1s;
        *(short8*)&lv[0][vrow0][vpart0 * 8] = v0s;
        *(short8*)&lv[0][vrow1][vpart1 * 8] = v1s;
    }
    __syncthreads();

    int cur = 0;
    for (int win = 0; win < 16; ++win) {
        short8 bst0, bst1, vst0, vst1;
        if (win < 15) {                              // issue next window early
            const int s0n = (win + 1) * 256;
            bst0 = *(const short8*)(gB0 + (size_t)s0n * CI_);
            bst1 = *(const short8*)(gB1 + (size_t)s0n * CI_);
            vst0 = *(const short8*)(gV0 + s0n);
            vst1 = *(const short8*)(gV1 + s0n);
        }
        // ---- compute window `win` from buffer `cur` ----
        __builtin_amdgcn_s_setprio(1);
#pragma unroll
        for (int ch2 = 0; ch2 < 2; ++ch2) {
            const int c0 = ch2 * 128 + cg * 32;      // window-local col base
            short8 b0 = *(const short8*)&lb[cur][c0 + lr][lg * 8];
            short8 b1 = *(const short8*)&lb[cur][c0 + 16 + lr][lg * 8];
            short4v v00 = *(const short4v*)&lv[cur][lr][c0 + lg * 4];
            short4v v01 = *(const short4v*)&lv[cur][lr][c0 + 16 + lg * 4];
            short4v v10 = *(const short4v*)&lv[cur][16 + lr][c0 + lg * 4];
            short4v v11 = *(const short4v*)&lv[cur][16 + lr][c0 + 16 + lg * 4];
            {   // t = 0 (m rows r0 + rg*32 + lr)
                float4v e0 = __builtin_amdgcn_mfma_f32_16x16x32_bf16(b0, afrag0, zero4, 0, 0, 0);
                float4v e1 = __builtin_amdgcn_mfma_f32_16x16x32_bf16(b1, afrag0, zero4, 0, 0, 0);
                float p0 = __builtin_amdgcn_exp2f(e0[0]), p1 = __builtin_amdgcn_exp2f(e0[1]);
                float p2 = __builtin_amdgcn_exp2f(e0[2]), p3 = __builtin_amdgcn_exp2f(e0[3]);
                float p4 = __builtin_amdgcn_exp2f(e1[0]), p5 = __builtin_amdgcn_exp2f(e1[1]);
                float p6 = __builtin_amdgcn_exp2f(e1[2]), p7 = __builtin_amdgcn_exp2f(e1[3]);
                bf16x4 q0, q1;
                q0[0] = (__bf16)p0; q0[1] = (__bf16)p1; q0[2] = (__bf16)p2; q0[3] = (__bf16)p3;
                q1[0] = (__bf16)p4; q1[1] = (__bf16)p5; q1[2] = (__bf16)p6; q1[3] = (__bf16)p7;
                short4v pk0 = __builtin_bit_cast(short4v, q0);
                short4v pk1 = __builtin_bit_cast(short4v, q1);
                a00  = mfma16(v00, pk0, a00);
                a00  = mfma16(v01, pk1, a00);
                a01  = mfma16(v10, pk0, a01);
                a01  = mfma16(v11, pk1, a01);
                sum0 = mfma16(ones, pk0, sum0);      // row r of D = colsum(P)
                sum0 = mfma16(ones, pk1, sum0);
            }
            {   // t = 1 (m rows r0 + rg*32 + 16 + lr)
                float4v e0 = __builtin_amdgcn_mfma_f32_16x16x32_bf16(b0, afrag1, zero4, 0, 0, 0);
                float4v e1 = __builtin_amdgcn_mfma_f32_16x16x32_bf16(b1, afrag1, zero4, 0, 0, 0);
                float p0 = __builtin_amdgcn_exp2f(e0[0]), p1 = __builtin_amdgcn_exp2f(e0[1]);
                float p2 = __builtin_amdgcn_exp2f(e0[2]), p3 = __builtin_amdgcn_exp2f(e0[3]);
                float p4 = __builtin_amdgcn_exp2f(e1[0]), p5 = __builtin_amdgcn_exp2f(e1[1]);
                float p6 = __builtin_amdgcn_exp2f(e1[2]), p7 = __builtin_amdgcn_exp2f(e1[3]);
                bf16x4 q0, q1;
                q0[0] = (__bf16)p0; q0[1] = (__bf16)p1; q0[2] = (__bf16)p2; q0[3] = (__bf16)p3;
                q1[0] = (__bf16)p4; q1[1] = (__bf16)p5; q1[2] = (__bf16)p6; q1[3] = (__bf16)p7;
                short4v pk0 = __builtin_bit_cast(short4v, q0);
                short4v pk1 = __builtin_bit_cast(short4v, q1);
                a10  = mfma16(v00, pk0, a10);
                a10  = mfma16(v01, pk1, a10);
                a11  = mfma16(v10, pk0, a11);
                a11  = mfma16(v11, pk1, a11);
                sum1 = mfma16(ones, pk0, sum1);
                sum1 = mfma16(ones, pk1, sum1);
            }
        }
        __builtin_amdgcn_s_setprio(0);
        if (win < 15) {                              // write-late into other buf
            *(short8*)&lb[cur ^ 1][brow0][bpart0 * 8] = bst0;
            *(short8*)&lb[cur ^ 1][brow1][bpart1 * 8] = bst1;
            *(short8*)&lv[cur ^ 1][vrow0][vpart0 * 8] = vst0;
            *(short8*)&lv[cur ^ 1][vrow1][vpart1 * 8] = vst1;
        }
        __syncthreads();                             // one barrier per window
        cur ^= 1;
    }

    // every lane's sum*[0] = exp-sum partial for its m-row (all rows of the
    // ones-MFMA D are identical); no cross-lane reduce needed.
    const float s0r = sum0[0];
    const float s1r = sum1[0];

    // (last barrier of the loop separates main-loop LDS use from overlays)
    if (cg >= 2) {                                   // seed buf2[cg-2]
        float* r0p = buf2[cg - 2][rg * 32 + lr];
        float* r1p = buf2[cg - 2][rg * 32 + 16 + lr];
#pragma unroll
        for (int i = 0; i < 4; ++i) {
            r0p[4 * lg + i]      = a00[i];
            r0p[16 + 4 * lg + i] = a01[i];
            r1p[4 * lg + i]      = a10[i];
            r1p[16 + 4 * lg + i] = a11[i];
        }
    }
    if (lane < 16) {
        sums[cg][rg * 32 + lane]      = s0r;
        sums[cg][rg * 32 + 16 + lane] = s1r;
    }
    for (int i = tid; i < C_ * CI_; i += 512) {      // fold output weights
        int co = i >> 5;
        float inv = w_bn[co] * rsqrtf(w_bn[192 + co] + EPS_);
        (&wf2[0][0])[i] = inv * Ww[i];               // flat [co][ci]
    }
    if (tid < C_) {
        float inv = w_bn[tid] * rsqrtf(w_bn[192 + tid] + EPS_);
        bf2v[tid] = inv * Wb[tid] + (w_bn[64 + tid] - w_bn[128 + tid] * inv);
    }
    __syncthreads();                                 // E1
    if (cg < 2) {                                    // add into buf2[cg]
        float* r0p = buf2[cg][rg * 32 + lr];
        float* r1p = buf2[cg][rg * 32 + 16 + lr];
#pragma unroll
        for (int i = 0; i < 4; ++i) {
            r0p[4 * lg + i]      += a00[i];
            r0p[16 + 4 * lg + i] += a01[i];
            r1p[4 * lg + i]      += a10[i];
            r1p[16 + 4 * lg + i] += a11[i];
        }
    }
    __syncthreads();                                 // E2
    {   // combine 2 buffers + 4 sums, normalize -> ybuf (512 thr: 4 elems)
        int m = tid >> 3;
        int ci0 = (tid & 7) * 4;
        float s = (sums[0][m] + sums[1][m]) + (sums[2][m] + sums[3][m]);
        float inv = 1.0f / s;
#pragma unroll
        for (int q = 0; q < 4; ++q) {
            ybuf[m][ci0 + q] = (buf2[0][m][ci0 + q] + buf2[1][m][ci0 + q]) * inv;
        }
    }
    __syncthreads();                                 // E3

    // fused output conv + BN + residual: out[co][m] = x[co][m] + sum_ci wf2*y
    const int m   = tid & 63;
    const int cog = tid >> 6;                        // wave handles co = 8*cog..+7
    float4v yq[8];
#pragma unroll
    for (int q = 0; q < 8; ++q) yq[q] = *(const float4v*)&ybuf[m][q * 4];
    const float* xb2 = (side ? x2 : x1) + (size_t)b * C_ * N_;
    float* ob = out + (size_t)side * (B_ * C_ * N_) + (size_t)b * C_ * N_;
#pragma unroll
    for (int k = 0; k < 8; ++k) {
        const int co = cog * 8 + k;
        float a2 = bf2v[co];
#pragma unroll
        for (int ci = 0; ci < CI_; ++ci) a2 += wf2[co][ci] * yq[ci >> 2][ci & 3];
        ob[(size_t)co * N_ + r0 + m] = xb2[(size_t)co * N_ + r0 + m] + a2;
    }
}

// ---------------------------------------------------------------------------
extern "C" void kernel_launch(void* const* d_in, const int* in_sizes, int n_in,
                              void* d_out, int out_size, void* d_ws, size_t ws_size,
                              hipStream_t stream)
{
    (void)in_sizes; (void)n_in; (void)out_size; (void)ws_size;
    const float* x1   = (const float*)d_in[0];
    const float* x2   = (const float*)d_in[1];
    const float* g_bn = (const float*)d_in[2];
    const float* g_w  = (const float*)d_in[3];
    const float* g_b  = (const float*)d_in[4];
    const float* t_bn = (const float*)d_in[5];
    const float* t_w  = (const float*)d_in[6];
    const float* t_b  = (const float*)d_in[7];
    const float* p_bn = (const float*)d_in[8];
    const float* p_w  = (const float*)d_in[9];
    const float* p_b  = (const float*)d_in[10];
    const float* w_bn = (const float*)d_in[11];
    const float* W_w  = (const float*)d_in[12];
    const float* W_b  = (const float*)d_in[13];
    float* out = (float*)d_out;

    char* ws = (char*)d_ws;
    const size_t MB = 1u << 20;
    short* th_t = (short*)(ws + 0 * MB);             // [B][N][32] bf16 (x log2e)
    short* ph_t = (short*)(ws + 1 * MB);             // [B][N][32] bf16
    short* g1l  = (short*)(ws + 2 * MB);             // [B][32][N] bf16
    short* g2l  = (short*)(ws + 3 * MB);             // [B][32][N] bf16

    proj_kernel<<<dim3(512), dim3(512), 0, stream>>>(
        x1, x2, g_w, g_b, g_bn, t_w, t_b, t_bn, p_w, p_b, p_bn,
        th_t, ph_t, g1l, g2l);

    apply_kernel<<<dim3(512), dim3(512), 0, stream>>>(
        th_t, ph_t, g1l, g2l, x1, x2, W_w, W_b, w_bn, out);
}

// Round 21
// 41.921 us; speedup vs baseline: 1.1660x; 1.1035x over previous
//
#include <hip/hip_runtime.h>
#include <hip/hip_bf16.h>
#include <cstdint>
#include <cstddef>

// Spatiotemporal dual-softmax attention, MI355X (gfx950).
// B=4, C=64, CI=32, N=H*W=4096. Flash-style, never materializes the 4096^2
// energy matrix. Round-21 = round-20 (best, 46.26 us) with ONE change:
// PV and sum accumulation use K=32 mfma_f32_16x16x32_bf16 instead of pairs
// of K=16 MFMAs. The lane's 8 P values (pk0||pk1) and 8 V values (v00||v01)
// share the same (lane,j)->n bijection over the 32-col chunk, so one K=32
// MFMA == the two K=16 MFMAs. Per (ch2,t): 8 MFMAs -> 5; the serial
// accumulator chain halves. V operands built by register shufflevector from
// the proven short4v LDS loads (no layout change). Everything else identical.
//   proj  (512 blk x 512): MFMA projections (r18-proven).
//   apply (512 blk x 512): XCD-aware remap (r20), 8 waves = 2 rg x 4 cg,
//         256-col windows x 16, 2-chunk inner loop, double-buffered LDS,
//         reg-staged issue-early / write-late (T14), one barrier per window.
//         Energy MFMA (swapped operands) -> exp2 (theta pre-scaled by log2e;
//         energies provably << 80, no max subtraction) -> bf16 pack ->
//         K=32 PV MFMA. Row-sums via ones-MFMA; s_setprio(1) around compute.
//         Epilogue: 4-way cg combine, normalize, output conv+BN+residual.

#define B_  4
#define C_  64
#define CI_ 32
#define N_  4096
static constexpr float EPS_   = 1e-5f;
static constexpr float LOG2E_ = 1.4426950408889634f;

typedef __attribute__((ext_vector_type(8))) short  short8;
typedef __attribute__((ext_vector_type(4))) short  short4v;
typedef __attribute__((ext_vector_type(4))) float  float4v;
typedef __attribute__((ext_vector_type(4))) __bf16 bf16x4;
typedef __attribute__((ext_vector_type(8))) __bf16 bf16x8;

__device__ __forceinline__ short f2bf(float f) {
    unsigned u = __float_as_uint(f);
    unsigned r = (u + 0x7fffu + ((u >> 16) & 1u)) >> 16;   // RNE
    return (short)r;
}

// ---------------------------------------------------------------------------
// MFMA projections (r18-proven). side = blk>>8: 0: x1 -> {theta*log2e, g1};
// 1: x2 -> {phi, g2}. theta/phi: [b][n][32] frag layout (scale folded into
// weights+bias); g: [b][32][n] row-major (V layout). 64 n-cols per block.
// 8 waves = set(2) x oTile(2) x nPair(2); each wave: 2 nTiles x 2 K-MFMAs.
// ---------------------------------------------------------------------------
__global__ __launch_bounds__(512) void proj_kernel(
    const float* __restrict__ x1, const float* __restrict__ x2,
    const float* __restrict__ g_w, const float* __restrict__ g_b, const float* __restrict__ g_bn,
    const float* __restrict__ t_w, const float* __restrict__ t_b, const float* __restrict__ t_bn,
    const float* __restrict__ p_w, const float* __restrict__ p_b, const float* __restrict__ p_bn,
    short* __restrict__ th_t, short* __restrict__ ph_t,
    short* __restrict__ g1l, short* __restrict__ g2l)
{
    const int side = blockIdx.x >> 8;
    const int rb   = blockIdx.x & 255;
    const int b    = rb >> 6;
    const int n0   = (rb & 63) * 64;
    const int tid  = threadIdx.x;
    const int wv   = tid >> 6, lane = tid & 63;
    const int lg   = lane >> 4, lr = lane & 15;

    const float* x   = side ? x2   : x1;
    const float* wA  = side ? p_w  : t_w;
    const float* bA  = side ? p_b  : t_b;
    const float* bnA = side ? p_bn : t_bn;
    short* outA      = side ? ph_t : th_t;
    short* outG      = side ? g2l  : g1l;
    const float scaleA = side ? 1.0f : LOG2E_;   // theta carries log2e

    __shared__ short xs_t[64][72];      // 9216 B  X^T: [n][c] bf16 (pad 72)
    __shared__ short wfb[2][32][72];    // 9216 B  [set][o][c] bf16 (pad 72)
    __shared__ float bfold[2][CI_];

    for (int it = 0; it < 4; it++) {                 // fold both weight sets
        int idx = it * 512 + tid;                    // [o][c] flat, 2048
        int o = idx >> 6, c = idx & 63;
        float invA = bnA[c]  * rsqrtf(bnA[192 + c]  + EPS_);
        float invG = g_bn[c] * rsqrtf(g_bn[192 + c] + EPS_);
        wfb[0][o][c] = f2bf(wA[idx]  * invA * scaleA);
        wfb[1][o][c] = f2bf(g_w[idx] * invG);
    }
    if (tid < 2 * CI_) {
        int set = tid >> 5, o = tid & 31;
        const float* bn = set ? g_bn : bnA;
        const float* w  = set ? g_w  : wA;
        const float* bs = set ? g_b  : bA;
        float s = bs[o];
        for (int c = 0; c < C_; c++) {
            float inv = bn[c] * rsqrtf(bn[192 + c] + EPS_);
            s += w[o * C_ + c] * (bn[64 + c] - bn[128 + c] * inv);
        }
        bfold[set][o] = set ? s : s * scaleA;
    }
    const float* xb = x + (size_t)b * C_ * N_ + n0;
    for (int it = 0; it < 2; it++) {                 // stage X^T as bf16
        int idx = it * 512 + tid;                    // 1024 float4 pieces
        int c = idx >> 4, nq = idx & 15;
        float4 xv = *(const float4*)(xb + (size_t)c * N_ + nq * 4);
        xs_t[nq * 4 + 0][c] = f2bf(xv.x);
        xs_t[nq * 4 + 1][c] = f2bf(xv.y);
        xs_t[nq * 4 + 2][c] = f2bf(xv.z);
        xs_t[nq * 4 + 3][c] = f2bf(xv.w);
    }
    __syncthreads();

    const int set = wv & 1;              // 0 = theta/phi, 1 = g
    const int oT  = (wv >> 1) & 1;       // o tile: o = oT*16 + lg*4 + i
    const int nP  = wv >> 2;             // n pair: nTiles {2nP, 2nP+1}

    const float4v zero4 = {0.f, 0.f, 0.f, 0.f};
    // W A-frags (lane: A[row = oT*16+lr][k = c0 + lg*8 + j])
    short8 wf0 = *(const short8*)&wfb[set][oT * 16 + lr][lg * 8];
    short8 wf1 = *(const short8*)&wfb[set][oT * 16 + lr][32 + lg * 8];
    float4v cinit = zero4;
#pragma unroll
    for (int i = 0; i < 4; ++i) cinit[i] = bfold[set][oT * 16 + lg * 4 + i];

#pragma unroll
    for (int t = 0; t < 2; ++t) {
        const int nT = nP * 2 + t;
        // X B-frags (lane: B[k = c0 + lg*8 + j][col = nT*16 + lr])
        short8 xf0 = *(const short8*)&xs_t[nT * 16 + lr][lg * 8];
        short8 xf1 = *(const short8*)&xs_t[nT * 16 + lr][32 + lg * 8];
        float4v d = __builtin_amdgcn_mfma_f32_16x16x32_bf16(wf0, xf0, cinit, 0, 0, 0);
        d = __builtin_amdgcn_mfma_f32_16x16x32_bf16(wf1, xf1, d, 0, 0, 0);
        // d[i] = out[o = oT*16 + lg*4 + i][n = n0 + nT*16 + lr]
        const int n = n0 + nT * 16 + lr;
        if (set == 0) {
            short4v v;
#pragma unroll
            for (int i = 0; i < 4; ++i) v[i] = f2bf(d[i]);
            *(short4v*)(outA + ((size_t)b * N_ + n) * CI_ + oT * 16 + lg * 4) = v;
        } else {
#pragma unroll
            for (int i = 0; i < 4; ++i)
                outG[((size_t)b * CI_ + oT * 16 + lg * 4 + i) * N_ + n] = f2bf(d[i]);
        }
    }
}

// ---------------------------------------------------------------------------
// Apply (fused softmax-sum + PV + output conv + residual).
// XCD-aware decode: g = bid&7 -> (side,b) group pinned to one XCD's L2;
// j = bid>>3 -> r0-block. 8 waves = 2 rg x 4 cg. Per 256-col window, wave
// (rg,cg) computes its 32 m-rows against chunks ch2*128 + cg*32, ch2 = 0,1.
// Double-buffered LDS; reg-staged issue-early / write-late; ONE barrier per
// window. PV + sums via K=32 MFMAs (matched per-lane k-permutation).
// ---------------------------------------------------------------------------
__global__ __launch_bounds__(512, 6) void apply_kernel(
    const short* __restrict__ th, const short* __restrict__ ph,
    const short* __restrict__ g1l, const short* __restrict__ g2l,
    const float* __restrict__ x1, const float* __restrict__ x2,
    const float* __restrict__ Ww, const float* __restrict__ Wb,
    const float* __restrict__ w_bn,
    float* __restrict__ out)
{
    const int bid  = blockIdx.x;
    const int grp  = bid & 7;               // (side,b) group -> XCD affinity
    const int side = grp >> 2;
    const int b    = grp & 3;
    const int r0   = (bid >> 3) * 64;
    const short* A  = side ? th : ph;       // rows = softmax/output dim (m)
    const short* Bm = side ? ph : th;       // cols = reduction dim (n)
    const short* V  = side ? g2l : g1l;
    const int tid = threadIdx.x;
    const int wv = tid >> 6, lane = tid & 63;
    const int cg = wv & 3, rg = wv >> 2;
    const int lg = lane >> 4, lr = lane & 15;

    // main loop: lb [2][256][40]s = 40960 | lv [2][32][264]s = 33792 -> 74752
    __shared__ __align__(16) char smem[74752];
    short (*lb)[256][40] = (short(*)[256][40])smem;
    short (*lv)[32][264] = (short(*)[32][264])(smem + 40960);
    // epilogue overlays (dead vs main loop across barriers)
    float (*buf2)[64][33] = (float(*)[64][33])smem;            // 16896
    float (*sums)[64]     = (float(*)[64])(smem + 16896);      //  1024
    float (*ybuf)[36]     = (float(*)[36])(smem + 17920);      //  9216
    float (*wf2)[CI_]     = (float(*)[CI_])(smem + 27136);     //  8192
    float *bf2v           = (float*)(smem + 35328);            //   256

    const short* Ab = A  + (size_t)b * N_ * CI_;
    const short* Bb = Bm + (size_t)b * N_ * CI_;
    const short* Vb = V  + (size_t)b * CI_ * N_;

    short8 afrag0 = *(const short8*)(Ab + (size_t)(r0 + rg * 32 + lr) * CI_ + lg * 8);
    short8 afrag1 = *(const short8*)(Ab + (size_t)(r0 + rg * 32 + 16 + lr) * CI_ + lg * 8);

    short8 ones8;
#pragma unroll
    for (int i = 0; i < 8; ++i) ones8[i] = (short)0x3F80;    // bf16 1.0

    const float4v zero4 = {0.f, 0.f, 0.f, 0.f};
    float4v a00 = zero4, a01 = zero4;   // t=0: y[ci=4lg+i][m], y[16+4lg+i][m]
    float4v a10 = zero4, a11 = zero4;   // t=1 (m + 16)
    float4v sum0 = zero4, sum1 = zero4; // ones-MFMA sum accumulators

    // staging: 256x32 B (1024 pieces) + 32x256 V (1024 pieces), 2 each/thread
    const int brow0 = tid >> 2,          bpart0 = tid & 3;          // it=0
    const int brow1 = (512 + tid) >> 2,  bpart1 = (512 + tid) & 3;  // it=1
    const int vrow0 = tid >> 5,          vpart0 = tid & 31;
    const int vrow1 = (512 + tid) >> 5,  vpart1 = (512 + tid) & 31;
    const short* gB0 = Bb + (size_t)brow0 * CI_ + bpart0 * 8;
    const short* gB1 = Bb + (size_t)brow1 * CI_ + bpart1 * 8;
    const short* gV0 = Vb + (size_t)vrow0 * N_ + vpart0 * 8;
    const short* gV1 = Vb + (size_t)vrow1 * N_ + vpart1 * 8;

    {   // prologue: stage window 0 into buffer 0
        short8 b0s = *(const short8*)gB0;
        short8 b1s = *(const short8*)gB1;
        short8 v0s = *(const short8*)gV0;
        short8 v1s = *(const short8*)gV1;
        *(short8*)&lb[0][brow0][bpart0 * 8] = b0s;
        *(short8*)&lb[0][brow1][bpart1 * 8] = b1s;
        *(short8*)&lv[0][vrow0][vpart0 * 8] = v0s;
        *(short8*)&lv[0][vrow1][vpart1 * 8] = v1s;
    }
    __syncthreads();

    int cur = 0;
    for (int win = 0; win < 16; ++win) {
        short8 bst0, bst1, vst0, vst1;
        if (win < 15) {                              // issue next window early
            const int s0n = (win + 1) * 256;
            bst0 = *(const short8*)(gB0 + (size_t)s0n * CI_);
            bst1 = *(const short8*)(gB1 + (size_t)s0n * CI_);
            vst0 = *(const short8*)(gV0 + s0n);
            vst1 = *(const short8*)(gV1 + s0n);
        }
        // ---- compute window `win` from buffer `cur` ----
        __builtin_amdgcn_s_setprio(1);
#pragma unroll
        for (int ch2 = 0; ch2 < 2; ++ch2) {
            const int c0 = ch2 * 128 + cg * 32;      // window-local col base
            short8 b0 = *(const short8*)&lb[cur][c0 + lr][lg * 8];
            short8 b1 = *(const short8*)&lb[cur][c0 + 16 + lr][lg * 8];
            short4v v00 = *(const short4v*)&lv[cur][lr][c0 + lg * 4];
            short4v v01 = *(const short4v*)&lv[cur][lr][c0 + 16 + lg * 4];
            short4v v10 = *(const short4v*)&lv[cur][16 + lr][c0 + lg * 4];
            short4v v11 = *(const short4v*)&lv[cur][16 + lr][c0 + 16 + lg * 4];
            // V A-operands with the SAME per-lane k->n permutation as P:
            // j=0..3 -> n=c0+4lg+j, j=4..7 -> n=c0+16+4lg+(j-4)
            short8 vA0 = __builtin_shufflevector(v00, v01, 0, 1, 2, 3, 4, 5, 6, 7);
            short8 vA1 = __builtin_shufflevector(v10, v11, 0, 1, 2, 3, 4, 5, 6, 7);
            {   // t = 0 (m rows r0 + rg*32 + lr)
                float4v e0 = __builtin_amdgcn_mfma_f32_16x16x32_bf16(b0, afrag0, zero4, 0, 0, 0);
                float4v e1 = __builtin_amdgcn_mfma_f32_16x16x32_bf16(b1, afrag0, zero4, 0, 0, 0);
                float p0 = __builtin_amdgcn_exp2f(e0[0]), p1 = __builtin_amdgcn_exp2f(e0[1]);
                float p2 = __builtin_amdgcn_exp2f(e0[2]), p3 = __builtin_amdgcn_exp2f(e0[3]);
                float p4 = __builtin_amdgcn_exp2f(e1[0]), p5 = __builtin_amdgcn_exp2f(e1[1]);
                float p6 = __builtin_amdgcn_exp2f(e1[2]), p7 = __builtin_amdgcn_exp2f(e1[3]);
                bf16x8 q;
                q[0] = (__bf16)p0; q[1] = (__bf16)p1; q[2] = (__bf16)p2; q[3] = (__bf16)p3;
                q[4] = (__bf16)p4; q[5] = (__bf16)p5; q[6] = (__bf16)p6; q[7] = (__bf16)p7;
                short8 pk = __builtin_bit_cast(short8, q);
                a00  = __builtin_amdgcn_mfma_f32_16x16x32_bf16(vA0, pk, a00, 0, 0, 0);
                a01  = __builtin_amdgcn_mfma_f32_16x16x32_bf16(vA1, pk, a01, 0, 0, 0);
                sum0 = __builtin_amdgcn_mfma_f32_16x16x32_bf16(ones8, pk, sum0, 0, 0, 0);
            }
            {   // t = 1 (m rows r0 + rg*32 + 16 + lr)
                float4v e0 = __builtin_amdgcn_mfma_f32_16x16x32_bf16(b0, afrag1, zero4, 0, 0, 0);
                float4v e1 = __builtin_amdgcn_mfma_f32_16x16x32_bf16(b1, afrag1, zero4, 0, 0, 0);
                float p0 = __builtin_amdgcn_exp2f(e0[0]), p1 = __builtin_amdgcn_exp2f(e0[1]);
                float p2 = __builtin_amdgcn_exp2f(e0[2]), p3 = __builtin_amdgcn_exp2f(e0[3]);
                float p4 = __builtin_amdgcn_exp2f(e1[0]), p5 = __builtin_amdgcn_exp2f(e1[1]);
                float p6 = __builtin_amdgcn_exp2f(e1[2]), p7 = __builtin_amdgcn_exp2f(e1[3]);
                bf16x8 q;
                q[0] = (__bf16)p0; q[1] = (__bf16)p1; q[2] = (__bf16)p2; q[3] = (__bf16)p3;
                q[4] = (__bf16)p4; q[5] = (__bf16)p5; q[6] = (__bf16)p6; q[7] = (__bf16)p7;
                short8 pk = __builtin_bit_cast(short8, q);
                a10  = __builtin_amdgcn_mfma_f32_16x16x32_bf16(vA0, pk, a10, 0, 0, 0);
                a11  = __builtin_amdgcn_mfma_f32_16x16x32_bf16(vA1, pk, a11, 0, 0, 0);
                sum1 = __builtin_amdgcn_mfma_f32_16x16x32_bf16(ones8, pk, sum1, 0, 0, 0);
            }
        }
        __builtin_amdgcn_s_setprio(0);
        if (win < 15) {                              // write-late into other buf
            *(short8*)&lb[cur ^ 1][brow0][bpart0 * 8] = bst0;
            *(short8*)&lb[cur ^ 1][brow1][bpart1 * 8] = bst1;
            *(short8*)&lv[cur ^ 1][vrow0][vpart0 * 8] = vst0;
            *(short8*)&lv[cur ^ 1][vrow1][vpart1 * 8] = vst1;
        }
        __syncthreads();                             // one barrier per window
        cur ^= 1;
    }

    // every lane's sum*[0] = exp-sum partial for its m-row (all rows of the
    // ones-MFMA D are identical); no cross-lane reduce needed.
    const float s0r = sum0[0];
    const float s1r = sum1[0];

    // (last barrier of the loop separates main-loop LDS use from overlays)
    if (cg >= 2) {                                   // seed buf2[cg-2]
        float* r0p = buf2[cg - 2][rg * 32 + lr];
        float* r1p = buf2[cg - 2][rg * 32 + 16 + lr];
#pragma unroll
        for (int i = 0; i < 4; ++i) {
            r0p[4 * lg + i]      = a00[i];
            r0p[16 + 4 * lg + i] = a01[i];
            r1p[4 * lg + i]      = a10[i];
            r1p[16 + 4 * lg + i] = a11[i];
        }
    }
    if (lane < 16) {
        sums[cg][rg * 32 + lane]      = s0r;
        sums[cg][rg * 32 + 16 + lane] = s1r;
    }
    for (int i = tid; i < C_ * CI_; i += 512) {      // fold output weights
        int co = i >> 5;
        float inv = w_bn[co] * rsqrtf(w_bn[192 + co] + EPS_);
        (&wf2[0][0])[i] = inv * Ww[i];               // flat [co][ci]
    }
    if (tid < C_) {
        float inv = w_bn[tid] * rsqrtf(w_bn[192 + tid] + EPS_);
        bf2v[tid] = inv * Wb[tid] + (w_bn[64 + tid] - w_bn[128 + tid] * inv);
    }
    __syncthreads();                                 // E1
    if (cg < 2) {                                    // add into buf2[cg]
        float* r0p = buf2[cg][rg * 32 + lr];
        float* r1p = buf2[cg][rg * 32 + 16 + lr];
#pragma unroll
        for (int i = 0; i < 4; ++i) {
            r0p[4 * lg + i]      += a00[i];
            r0p[16 + 4 * lg + i] += a01[i];
            r1p[4 * lg + i]      += a10[i];
            r1p[16 + 4 * lg + i] += a11[i];
        }
    }
    __syncthreads();                                 // E2
    {   // combine 2 buffers + 4 sums, normalize -> ybuf (512 thr: 4 elems)
        int m = tid >> 3;
        int ci0 = (tid & 7) * 4;
        float s = (sums[0][m] + sums[1][m]) + (sums[2][m] + sums[3][m]);
        float inv = 1.0f / s;
#pragma unroll
        for (int q = 0; q < 4; ++q) {
            ybuf[m][ci0 + q] = (buf2[0][m][ci0 + q] + buf2[1][m][ci0 + q]) * inv;
        }
    }
    __syncthreads();                                 // E3

    // fused output conv + BN + residual: out[co][m] = x[co][m] + sum_ci wf2*y
    const int m   = tid & 63;
    const int cog = tid >> 6;                        // wave handles co = 8*cog..+7
    float4v yq[8];
#pragma unroll
    for (int q = 0; q < 8; ++q) yq[q] = *(const float4v*)&ybuf[m][q * 4];
    const float* xb2 = (side ? x2 : x1) + (size_t)b * C_ * N_;
    float* ob = out + (size_t)side * (B_ * C_ * N_) + (size_t)b * C_ * N_;
#pragma unroll
    for (int k = 0; k < 8; ++k) {
        const int co = cog * 8 + k;
        float a2 = bf2v[co];
#pragma unroll
        for (int ci = 0; ci < CI_; ++ci) a2 += wf2[co][ci] * yq[ci >> 2][ci & 3];
        ob[(size_t)co * N_ + r0 + m] = xb2[(size_t)co * N_ + r0 + m] + a2;
    }
}

// ---------------------------------------------------------------------------
extern "C" void kernel_launch(void* const* d_in, const int* in_sizes, int n_in,
                              void* d_out, int out_size, void* d_ws, size_t ws_size,
                              hipStream_t stream)
{
    (void)in_sizes; (void)n_in; (void)out_size; (void)ws_size;
    const float* x1   = (const float*)d_in[0];
    const float* x2   = (const float*)d_in[1];
    const float* g_bn = (const float*)d_in[2];
    const float* g_w  = (const float*)d_in[3];
    const float* g_b  = (const float*)d_in[4];
    const float* t_bn = (const float*)d_in[5];
    const float* t_w  = (const float*)d_in[6];
    const float* t_b  = (const float*)d_in[7];
    const float* p_bn = (const float*)d_in[8];
    const float* p_w  = (const float*)d_in[9];
    const float* p_b  = (const float*)d_in[10];
    const float* w_bn = (const float*)d_in[11];
    const float* W_w  = (const float*)d_in[12];
    const float* W_b  = (const float*)d_in[13];
    float* out = (float*)d_out;

    char* ws = (char*)d_ws;
    const size_t MB = 1u << 20;
    short* th_t = (short*)(ws + 0 * MB);             // [B][N][32] bf16 (x log2e)
    short* ph_t = (short*)(ws + 1 * MB);             // [B][N][32] bf16
    short* g1l  = (short*)(ws + 2 * MB);             // [B][32][N] bf16
    short* g2l  = (short*)(ws + 3 * MB);             // [B][32][N] bf16

    proj_kernel<<<dim3(512), dim3(512), 0, stream>>>(
        x1, x2, g_w, g_b, g_bn, t_w, t_b, t_bn, p_w, p_b, p_bn,
        th_t, ph_t, g1l, g2l);

    apply_kernel<<<dim3(512), dim3(512), 0, stream>>>(
        th_t, ph_t, g1l, g2l, x1, x2, W_w, W_b, w_bn, out);
}